// Round 5
// baseline (106.699 us; speedup 1.0000x reference)
//
#include <hip/hip_runtime.h>

// emb[b,n,i] = cos(pi * i * x[b,n]),  i = 0..127
// rows = b*n = 1,048,576 ; out row-major [rows][128] f32 (512 MiB -> write-bound).
//
// cos(pi*i*x) = cos(2*pi*(i*x/2)); v_cos_f32 takes REVOLUTIONS:
// val = v_cos(fract(x/2 * i)) -- fract is an exact period reduction.
//
// Round-5: persistent fill-style kernel. Evidence: fill kernel hits 6.88 TB/s
// at 10% occupancy with long-lived waves streaming stores; our one-shot waves
// (rounds 3/4, both 104 us) cluster 8 stores at end-of-life after a ~1300cy
// silent prologue -> average outstanding-store bytes/CU too low to cover
// write latency. Here each wave loops 8x {compute float4 -> store}, with the
// NEXT iteration's x prefetched at loop top and consumed only after this
// iteration's stores (no dependent stall; stores never waited on, vmcnt
// stays deep across iterations). Coalescing mapping unchanged from round 4:
// each wave store = contiguous aligned 1 KiB (round-2 lesson).

typedef float f32x4 __attribute__((ext_vector_type(4)));

__global__ __launch_bounds__(256) void Emb_37967510896970_kernel(
    const float* __restrict__ x, f32x4* __restrict__ out, int total_rows)
{
    const int tid  = threadIdx.x;
    const int ty   = tid >> 5;               // 0..7: row group within block
    const int slot = tid & 31;               // float4 slot within row
    const float i0 = (float)(slot << 2);
    const int stride_rows = (int)gridDim.x * 64;   // rows per sweep

    int base = blockIdx.x * 64;              // this block's row base

    // prologue: load first batch (clamped)
    float h[8];
#pragma unroll
    for (int q = 0; q < 8; ++q) {
        int r = base + ty + 8 * q;
        h[q] = 0.5f * x[r < total_rows ? r : 0];
    }

    for (; base < total_rows; base += stride_rows) {
        // prefetch next sweep's x early; consumed only after the stores below
        const int nb = base + stride_rows;
        float hn[8];
        if (nb < total_rows) {
#pragma unroll
            for (int q = 0; q < 8; ++q) {
                int r = nb + ty + 8 * q;
                hn[q] = 0.5f * x[r < total_rows ? r : 0];
            }
        }

        // compute+store interleaved: store flows continuously, 1 KiB/wave/store
        f32x4* p = out + (size_t)base * 32 + tid;
#pragma unroll
        for (int q = 0; q < 8; ++q) {
            const float hq = h[q];
            const float hb = hq * i0;
            f32x4 v;
#pragma unroll
            for (int k = 0; k < 4; ++k)
                v[k] = __builtin_amdgcn_cosf(
                           __builtin_amdgcn_fractf(fmaf(hq, (float)k, hb)));
            int r = base + ty + 8 * q;
            if (r < total_rows)
                __builtin_nontemporal_store(v, p + q * 256);
        }

        // shift pipeline (garbage if nb OOB, but loop exits then)
#pragma unroll
        for (int q = 0; q < 8; ++q) h[q] = hn[q];
    }
}

extern "C" void kernel_launch(void* const* d_in, const int* in_sizes, int n_in,
                              void* d_out, int out_size, void* d_ws, size_t ws_size,
                              hipStream_t stream) {
    const float* x = (const float*)d_in[0];
    f32x4* out = (f32x4*)d_out;
    const int total_rows = in_sizes[0];      // 1,048,576
    const int grid = 2048;                   // 8 blocks/CU resident, 8 sweeps
    Emb_37967510896970_kernel<<<grid, 256, 0, stream>>>(x, out, total_rows);
}

// Round 6
// 102.734 us; speedup vs baseline: 1.0386x; 1.0386x over previous
//
#include <hip/hip_runtime.h>

// emb[b,n,i] = cos(pi * i * x[b,n]),  i = 0..127
// rows = b*n = 1,048,576 ; out row-major [rows][128] f32 (512 MiB -> write-bound).
//
// cos(pi*i*x) = cos(2*pi*(i*x/2)); v_cos_f32 takes REVOLUTIONS:
// val = v_cos(fract(x/2 * i)) -- fract is an exact period reduction.
//
// Round-6: fill-mimic concurrency geometry. Evidence: rocclr fill sustains
// 6.88 TB/s at OccupancyPercent ~10.8 (≈1 block/CU, few long-lived waves,
// contiguous strided sweeps); every full-occupancy variant of ours (one-shot
// or persistent, 32 waves/CU) pins at 5.2 TB/s. Hypothesis: thousands of
// concurrent 1-KiB wave-streams wreck DRAM row/bank locality; fewer, longer
// streams drain near-sequentially. Grid = 512 (2 blocks/CU, 8 waves/CU),
// 256 sweeps; per sweep a wave writes one contiguous 1 KiB line, sweep
// stride 2 MiB. Depth-2 pipelined x loads: the h0=h1 rotation's vmcnt wait
// lands after the store issues, one full iteration of slack.

typedef float f32x4 __attribute__((ext_vector_type(4)));

__global__ __launch_bounds__(256) void Emb_37967510896970_kernel(
    const float* __restrict__ x, f32x4* __restrict__ out,
    int total_rows, int nsweeps)
{
    const int tid  = threadIdx.x;
    const int ty   = tid >> 5;               // 0..7: row within block-sweep
    const int slot = tid & 31;               // float4 slot within row
    const float i0 = (float)(slot << 2);

    const int rstep = (int)gridDim.x * 8;    // rows advanced per sweep (4096)
    int row = blockIdx.x * 8 + ty;

    // depth-2 software pipeline on the x loads (x: 4 MiB, L2-resident)
    float h0 = 0.5f * x[row < total_rows ? row : 0];
    int r1 = row + rstep;
    float h1 = 0.5f * x[r1 < total_rows ? r1 : 0];

    f32x4* __restrict__ p = out + (size_t)blockIdx.x * 256 + tid;
    const size_t pstep = (size_t)gridDim.x * 256;   // f4 per sweep (131072)

    for (int s = 0; s < nsweeps; ++s) {
        // prefetch sweep s+2 (clamped; garbage beyond end, never consumed)
        int r2 = row + 2 * rstep;
        float hn = 0.5f * x[r2 < total_rows ? r2 : 0];

        // compute + store sweep s: wave store = contiguous 1 KiB
        const float hb = h0 * i0;
        f32x4 v;
#pragma unroll
        for (int k = 0; k < 4; ++k)
            v[k] = __builtin_amdgcn_cosf(
                       __builtin_amdgcn_fractf(fmaf(h0, (float)k, hb)));
        if (row < total_rows)
            __builtin_nontemporal_store(v, p);

        p += pstep;
        row += rstep;
        h0 = h1;          // vmcnt wait for h1 happens here, after the store
        h1 = hn;
    }
}

extern "C" void kernel_launch(void* const* d_in, const int* in_sizes, int n_in,
                              void* d_out, int out_size, void* d_ws, size_t ws_size,
                              hipStream_t stream) {
    const float* x = (const float*)d_in[0];
    f32x4* out = (f32x4*)d_out;
    const int total_rows = in_sizes[0];              // 1,048,576
    const int grid = 512;                            // 2 blocks/CU: few, long streams
    const int rows_per_sweep = grid * 8;             // 4096
    const int nsweeps = (total_rows + rows_per_sweep - 1) / rows_per_sweep; // 256
    Emb_37967510896970_kernel<<<grid, 256, 0, stream>>>(x, out, total_rows, nsweeps);
}